// Round 14
// baseline (1097.778 us; speedup 1.0000x reference)
//
#include <hip/hip_runtime.h>
#include <math.h>

#define NN 100000
#define NE 3200000
#define NG 512
#define NWELEM 26114
#define NBUK 49        // ceil(NN / 2048)

__device__ __forceinline__ float b2f(unsigned short u) {
    union { float f; unsigned int i; } c; c.i = ((unsigned int)u) << 16; return c.f;
}
__device__ __forceinline__ unsigned short f2b(float f) {
    union { float f; unsigned int i; } c; c.f = f;
    unsigned int r = c.i + 0x7FFFu + ((c.i >> 16) & 1u);   // RNE
    return (unsigned short)(r >> 16);
}

// ---------------- dtype detection ----------------
__global__ void k_detect_f(const unsigned short* __restrict__ u, int n,
                           int* __restrict__ c0, int* __restrict__ c1) {
    int t = blockIdx.x * blockDim.x + threadIdx.x;
    int a = 0, b = 0;
    for (int i = t; i < n; i += gridDim.x * blockDim.x) {
        float v = b2f(u[i]);
        if (!isfinite(v) || fabsf(v) > 1.0e4f) a++;
        if (((i & 1) == 0) && u[i] == 0) b++;
    }
    if (a) atomicAdd(c0, a);
    if (b) atomicAdd(c1, b);
}
__global__ void k_detect_odd(const int* __restrict__ p, int base, int n,
                             int* __restrict__ c) {
    int t = blockIdx.x * blockDim.x + threadIdx.x;
    int a = 0;
    for (int i = t; i < n; i += gridDim.x * blockDim.x)
        if (p[base + 2 * i + 1] != 0) a++;
    if (a) atomicAdd(c, a);
}
__global__ void k_flags(int* __restrict__ cnt) {
    cnt[8]  = (cnt[0] > 50 || cnt[1] > 8000) ? 1 : 0;   // x fp32
    cnt[9]  = (cnt[2] > 50 || cnt[3] > 1000) ? 1 : 0;   // W fp32
    cnt[10] = (cnt[4] < 100) ? 1 : 0;                   // edges int64
    cnt[11] = (cnt[5] < 100) ? 1 : 0;                   // batch int64
}

// ---------------- edge accessors ----------------
__device__ __forceinline__ int e_src(const int* ei, long e, bool i64) {
    return i64 ? ei[2 * e] : ei[e];
}
__device__ __forceinline__ int e_dst(const int* ei, long e, bool i64) {
    return i64 ? ei[2 * ((long)NE + e)] : ei[(long)NE + e];
}

// ---------------- canonicalization ----------------
__global__ void k_conv_x8(const void* __restrict__ p, float* __restrict__ dst,
                          const int* __restrict__ flags) {
    int i = blockIdx.x * blockDim.x + threadIdx.x;
    if (i >= NN * 8) return;
    int node = i >> 3, f = i & 7;
    float v = 0.f;
    if (f < 6)
        v = flags[8] ? ((const float*)p)[node * 6 + f]
                     : b2f(((const unsigned short*)p)[node * 6 + f]);
    dst[i] = v;
}
__global__ void k_conv_batch(const int* __restrict__ b, int* __restrict__ b32,
                             const int* __restrict__ flags) {
    int i = blockIdx.x * blockDim.x + threadIdx.x;
    if (i >= NN) return;
    b32[i] = flags[11] ? b[2 * i] : b[i];
}
struct WPtrs { const void* p[19]; };
__global__ void k_conv_w(WPtrs wp, float* __restrict__ dst, const int* __restrict__ flags) {
    const int L[19] = {384, 64, 384, 4096, 64, 4096, 4096, 64, 4096,
                       64, 64, 64, 64, 64, 64, 8192, 64, 128, 2};
    bool f32 = flags[9];
    int i = blockIdx.x * blockDim.x + threadIdx.x;
    if (i >= NWELEM) return;
    int ti = 0, off = i;
    while (off >= L[ti]) { off -= L[ti]; ti++; }
    const void* p = wp.p[ti];
    dst[i] = f32 ? ((const float*)p)[off] : b2f(((const unsigned short*)p)[off]);
}

// ---------------- CSR build ----------------
__global__ void k_hist(const int* __restrict__ ei, const int* __restrict__ flags,
                       int* __restrict__ counts) {
    long e = (long)blockIdx.x * blockDim.x + threadIdx.x;
    if (e >= NE) return;
    int d = e_dst(ei, e, flags[10]);
    if ((unsigned)d < NN) atomicAdd(&counts[d], 1);
}

// ---------------- scans ----------------
__global__ void k_scan_block(const int* __restrict__ counts, int* __restrict__ inblk,
                             int* __restrict__ btot) {
    __shared__ int s[256];
    int t = threadIdx.x;
    int idx = blockIdx.x * 256 + t;
    int v = (idx < NN) ? counts[idx] : 0;
    s[t] = v;
    __syncthreads();
    for (int off = 1; off < 256; off <<= 1) {
        int x = (t >= off) ? s[t - off] : 0;
        __syncthreads();
        s[t] += x;
        __syncthreads();
    }
    if (idx < NN) inblk[idx] = s[t] - v;
    if (t == 255) btot[blockIdx.x] = s[255];
}
__global__ void k_scan_top(const int* __restrict__ btot, int* __restrict__ boff, int nb) {
    __shared__ int s[512];
    int t = threadIdx.x;
    int v = (t < nb) ? btot[t] : 0;
    s[t] = v;
    __syncthreads();
    for (int off = 1; off < 512; off <<= 1) {
        int x = (t >= off) ? s[t - off] : 0;
        __syncthreads();
        s[t] += x;
        __syncthreads();
    }
    if (t < nb) boff[t] = s[t] - v;
}
__global__ void k_scan_final(const int* __restrict__ inblk, const int* __restrict__ boff,
                             int* __restrict__ rowptr, int* __restrict__ cursor) {
    int idx = blockIdx.x * 256 + threadIdx.x;
    if (idx < NN) {
        int r = inblk[idx] + boff[blockIdx.x];
        rowptr[idx] = r;
        cursor[idx] = r;
    }
    if (idx == 0) rowptr[NN] = NE;
}
__global__ void k_bukinit(const int* __restrict__ rowptr, int* __restrict__ bukcur) {
    int t = threadIdx.x;
    if (t < NBUK) bukcur[t] = rowptr[t * 2048];
}

// pass A: bin edges by dst>>11 into binbuf (packed (dst<<32)|src), NT stores.
__global__ void k_binA(const int* __restrict__ ei, const int* __restrict__ flags,
                       int* __restrict__ bukcur, unsigned long long* __restrict__ binbuf) {
    __shared__ int lh[NBUK], lbase[NBUK], lcur[NBUK];
    int t = threadIdx.x;
    bool i64 = flags[10];
    const long chunk = (NE + gridDim.x - 1) / gridDim.x;
    long e0 = (long)blockIdx.x * chunk;
    long e1 = e0 + chunk; if (e1 > NE) e1 = NE;
    for (int b = t; b < NBUK; b += 256) lh[b] = 0;
    __syncthreads();
    for (long e = e0 + t; e < e1; e += 256) {
        int d = e_dst(ei, e, i64);
        if ((unsigned)d < NN) atomicAdd(&lh[d >> 11], 1);
    }
    __syncthreads();
    for (int b = t; b < NBUK; b += 256) {
        lbase[b] = lh[b] ? atomicAdd(&bukcur[b], lh[b]) : 0;
        lcur[b] = 0;
    }
    __syncthreads();
    for (long e = e0 + t; e < e1; e += 256) {
        int d = e_dst(ei, e, i64);
        if ((unsigned)d < NN) {
            int s = e_src(ei, e, i64);
            int b = d >> 11;
            int off = atomicAdd(&lcur[b], 1);
            unsigned long long v = ((unsigned long long)(unsigned)d << 32) |
                                   (unsigned)(((unsigned)s < NN) ? s : 0);
            __builtin_nontemporal_store(v, &binbuf[(long)lbase[b] + off]);
        }
    }
}

// pass B: fine scatter from bucket-ordered binbuf. XCD-contiguous slices:
// all blocks with the same (blockIdx&7) cover one contiguous NE/8 range, so
// each XCD group's csr window (~1.6MB) stays L2-resident; NT loads keep the
// binbuf stream out of L2.
__global__ void k_binB(const unsigned long long* __restrict__ binbuf,
                       int* __restrict__ cursor, int* __restrict__ csr) {
    int x = blockIdx.x & 7;
    int g = blockIdx.x >> 3;
    int ng = gridDim.x >> 3;
    long lo = (long)x * (NE / 8), hi = lo + (NE / 8);
    for (long e = lo + (long)g * blockDim.x + threadIdx.x; e < hi;
         e += (long)ng * blockDim.x) {
        unsigned long long v = __builtin_nontemporal_load(&binbuf[e]);
        int d = (int)(v >> 32);
        int s = (int)(v & 0xffffffffu);
        int p = atomicAdd(&cursor[d], 1);
        if (p >= 0 && p < NE) csr[p] = s;
    }
}

// ---------------- aggregation ----------------
__global__ void k_agg6(const float* __restrict__ x8, const int* __restrict__ rowptr,
                       const int* __restrict__ csr, float* __restrict__ agg) {
    int gt = blockIdx.x * blockDim.x + threadIdx.x;
    int node = gt >> 6;
    if (node >= NN) return;
    int lane = threadIdx.x & 63;
    int f = lane & 7, es = lane >> 3;
    int r0 = rowptr[node], r1 = rowptr[node + 1];
    float acc = 0.f;
    for (int e = r0 + es; e < r1; e += 8) {
        int s = csr[e];
        acc += x8[s * 8 + f];
    }
    acc += __shfl_xor(acc, 8);
    acc += __shfl_xor(acc, 16);
    acc += __shfl_xor(acc, 32);
    int deg = r1 - r0;
    if (lane < 8) agg[node * 8 + lane] = acc / (float)(deg > 0 ? deg : 1);
}
// vectorized: lane = (row-half, channel-pair); one uint load = 2 bf16;
// wave fetches 2 source rows (256B) per iteration.
__global__ void k_agg64b(const unsigned short* __restrict__ hb,
                         const int* __restrict__ rowptr,
                         const int* __restrict__ csr, float* __restrict__ agg) {
    int gt = blockIdx.x * blockDim.x + threadIdx.x;
    int node = gt >> 6;
    if (node >= NN) return;
    int lane = threadIdx.x & 63;
    int c2 = lane & 31;        // channels 2*c2, 2*c2+1
    int half = lane >> 5;      // which row of the edge pair
    int r0 = rowptr[node], r1 = rowptr[node + 1];
    float ax = 0.f, ay = 0.f;
    for (int e = r0; e < r1; e += 2) {
        int er = e + half;
        if (er < r1) {
            int s = csr[er];
            unsigned u = *(const unsigned*)&hb[(long)s * 64 + 2 * c2];
            ax += b2f((unsigned short)(u & 0xffffu));
            ay += b2f((unsigned short)(u >> 16));
        }
    }
    ax += __shfl_xor(ax, 32);
    ay += __shfl_xor(ay, 32);
    if (half == 0) {
        int deg = r1 - r0;
        float inv = 1.0f / (float)(deg > 0 ? deg : 1);
        float2 o; o.x = ax * inv; o.y = ay * inv;
        *(float2*)&agg[(long)node * 64 + 2 * c2] = o;
    }
}

// ---------------- linear (+ fused BN stats) ----------------
__global__ void k_mm1(const float* __restrict__ agg6, const float* __restrict__ x8,
                      const float* __restrict__ Wl, const float* __restrict__ bl,
                      const float* __restrict__ Wr, float* __restrict__ pre,
                      double* __restrict__ part) {
    __shared__ float wl[6 * 64], wr[6 * 64];
    int t = threadIdx.x;
    for (int j = t; j < 384; j += 256) { wl[j] = Wl[j]; wr[j] = Wr[j]; }
    __syncthreads();
    int o = t & 63, rs = t >> 6;
    float bo = bl[o];
    double sm = 0.0, sq = 0.0;
    for (int i0 = blockIdx.x * 4; i0 < NN; i0 += gridDim.x * 4) {
        int i = i0 + rs;
        if (i < NN) {
            const float* m = &agg6[i * 8];
            const float* xr = &x8[i * 8];
            float p = bo;
#pragma unroll
            for (int k = 0; k < 6; k++) p += m[k] * wl[k * 64 + o] + xr[k] * wr[k * 64 + o];
            pre[(long)i * 64 + o] = p;
            sm += p;
            sq += (double)p * p;
        }
    }
    __shared__ double sd[256];
    sd[t] = sm; __syncthreads();
    if (t < 128) sd[t] += sd[t + 128];
    __syncthreads();
    if (t < 64) part[blockIdx.x * 128 + t] = sd[t] + sd[t + 64];
    __syncthreads();
    sd[t] = sq; __syncthreads();
    if (t < 128) sd[t] += sd[t + 128];
    __syncthreads();
    if (t < 64) part[blockIdx.x * 128 + 64 + t] = sd[t] + sd[t + 64];
}

// mm64b v3 (R13 winner): 4 rows/wave, LDS weights amortized, no local arrays.
__global__ void k_mm64b(const float* __restrict__ agg, const unsigned short* __restrict__ hb,
                        const float* __restrict__ Wl, const float* __restrict__ bl,
                        const float* __restrict__ Wr, float* __restrict__ pre,
                        double* __restrict__ part) {
    __shared__ float wl[4096], wr[4096];
    int t = threadIdx.x;
    for (int j = t; j < 4096; j += 256) { wl[j] = Wl[j]; wr[j] = Wr[j]; }
    __syncthreads();
    int o = t & 63, wv = t >> 6;
    float bo = bl[o];
    double sm = 0.0, sq = 0.0;
    for (int i0 = blockIdx.x * 16; i0 < NN; i0 += gridDim.x * 16) {
        long i = i0 + wv * 4;
        const float* m0 = agg + i * 64;
        const unsigned short* h0 = hb + i * 64;
        float a0 = bo, a1 = bo, a2 = bo, a3 = bo;
#pragma unroll 8
        for (int k = 0; k < 64; k++) {
            float wlv = wl[k * 64 + o];
            float wrv = wr[k * 64 + o];
            a0 += m0[k]       * wlv + b2f(h0[k])       * wrv;
            a1 += m0[64 + k]  * wlv + b2f(h0[64 + k])  * wrv;
            a2 += m0[128 + k] * wlv + b2f(h0[128 + k]) * wrv;
            a3 += m0[192 + k] * wlv + b2f(h0[192 + k]) * wrv;
        }
        pre[(i + 0) * 64 + o] = a0;
        pre[(i + 1) * 64 + o] = a1;
        pre[(i + 2) * 64 + o] = a2;
        pre[(i + 3) * 64 + o] = a3;
        sm += (double)a0 + (double)a1 + (double)a2 + (double)a3;
        sq += (double)a0 * a0 + (double)a1 * a1 + (double)a2 * a2 + (double)a3 * a3;
    }
    __shared__ double sd[256];
    sd[t] = sm; __syncthreads();
    if (t < 128) sd[t] += sd[t + 128];
    __syncthreads();
    if (t < 64) part[blockIdx.x * 128 + t] = sd[t] + sd[t + 64];
    __syncthreads();
    sd[t] = sq; __syncthreads();
    if (t < 128) sd[t] += sd[t + 128];
    __syncthreads();
    if (t < 64) part[blockIdx.x * 128 + 64 + t] = sd[t] + sd[t + 64];
}

__global__ void k_statred_p(const double* __restrict__ part, int nb,
                            float* __restrict__ mu, float* __restrict__ inv) {
    int c = blockIdx.x;
    int t = threadIdx.x;
    double sm = 0.0, sq = 0.0;
    for (int b = t; b < nb; b += 256) {
        sm += part[(long)b * 128 + c];
        sq += part[(long)b * 128 + 64 + c];
    }
    __shared__ double s1[256], s2[256];
    s1[t] = sm; s2[t] = sq;
    __syncthreads();
    for (int off = 128; off > 0; off >>= 1) {
        if (t < off) { s1[t] += s1[t + off]; s2[t] += s2[t + off]; }
        __syncthreads();
    }
    if (t == 0) {
        double m = s1[0] / (double)NN;
        double v = s2[0] / (double)NN - m * m;
        mu[c] = (float)m;
        inv[c] = (float)rsqrt(v + 1e-5);
    }
}

__global__ void k_bnrelu(float4* __restrict__ pre, ushort4* __restrict__ hb,
                         const float* __restrict__ mu, const float* __restrict__ inv,
                         const float* __restrict__ g, const float* __restrict__ be) {
    long idx = (long)blockIdx.x * blockDim.x + threadIdx.x;
    if (idx >= (long)NN * 16) return;
    int c = ((int)idx & 15) * 4;
    float4 p = pre[idx];
    p.x = fmaxf((p.x - mu[c + 0]) * inv[c + 0] * g[c + 0] + be[c + 0], 0.f);
    p.y = fmaxf((p.y - mu[c + 1]) * inv[c + 1] * g[c + 1] + be[c + 1], 0.f);
    p.z = fmaxf((p.z - mu[c + 2]) * inv[c + 2] * g[c + 2] + be[c + 2], 0.f);
    p.w = fmaxf((p.w - mu[c + 3]) * inv[c + 3] * g[c + 3] + be[c + 3], 0.f);
    pre[idx] = p;
    ushort4 u;
    u.x = f2b(p.x); u.y = f2b(p.y); u.z = f2b(p.z); u.w = f2b(p.w);
    hb[idx] = u;
}

// ---------------- pooling + MLP ----------------
__device__ __forceinline__ int lowb(const int* b, int n, int key) {
    int lo = 0, hi = n;
    while (lo < hi) {
        int m = (lo + hi) >> 1;
        if (b[m] < key) lo = m + 1; else hi = m;
    }
    return lo;
}
__global__ void k_pool(const float* __restrict__ h, const int* __restrict__ batch,
                       float* __restrict__ z) {
    int g = blockIdx.x;
    int t = threadIdx.x;
    int lo = lowb(batch, NN, g);
    int hi = lowb(batch, NN, g + 1);
    int c = t & 63, rs = t >> 6;
    float mx = 0.f, sm = 0.f;
    for (int i = lo + rs; i < hi; i += 4) {
        float v = h[(long)i * 64 + c];
        mx = fmaxf(mx, v);
        sm += v;
    }
    __shared__ float s1[256], s2[256];
    s1[t] = mx; s2[t] = sm;
    __syncthreads();
    if (t < 128) { s1[t] = fmaxf(s1[t], s1[t + 128]); s2[t] += s2[t + 128]; }
    __syncthreads();
    if (t < 64) {
        float M = fmaxf(s1[t], s1[t + 64]);
        float S = s2[t] + s2[t + 64];
        int n = hi - lo;
        z[g * 128 + t] = M;
        z[g * 128 + 64 + t] = S / (float)(n > 0 ? n : 1);
    }
}
__global__ void k_mlp(const float* __restrict__ z, const float* __restrict__ W1,
                      const float* __restrict__ b1, const float* __restrict__ W2,
                      const float* __restrict__ b2, float* __restrict__ out) {
    int g = blockIdx.x, t = threadIdx.x;
    __shared__ float zr[128], hid[64];
    zr[t] = z[g * 128 + t];
    zr[t + 64] = z[g * 128 + 64 + t];
    __syncthreads();
    float a = b1[t];
#pragma unroll 8
    for (int k = 0; k < 128; k++) a += zr[k] * W1[k * 64 + t];
    hid[t] = fmaxf(a, 0.f);
    __syncthreads();
    if (t < 2) {
        float o = b2[t];
#pragma unroll
        for (int k = 0; k < 64; k++) o += hid[k] * W2[k * 2 + t];
        out[g * 2 + t] = o;
    }
}

// ---------------- launch ----------------
static inline char* alignup(char* p, size_t a) {
    return (char*)(((uintptr_t)p + a - 1) & ~(uintptr_t)(a - 1));
}

extern "C" void kernel_launch(void* const* d_in, const int* in_sizes, int n_in,
                              void* d_out, int out_size, void* d_ws, size_t ws_size,
                              hipStream_t stream) {
    float* out = (float*)d_out;

    char* w = (char*)d_ws;
    int* dcnt   = (int*)w;            w = alignup(w + 64, 256);
    int* bukcur = (int*)w;            w = alignup(w + 256, 256);
    int* counts = (int*)w;            w = alignup(w + NN * 4, 256);
    int* cursor = (int*)w;            w = alignup(w + NN * 4, 256);
    int* inblk  = (int*)w;            w = alignup(w + NN * 4, 256);
    int* btot   = (int*)w;            w = alignup(w + 512 * 4, 256);
    int* boff   = (int*)w;            w = alignup(w + 512 * 4, 256);
    int* rowptr = (int*)w;            w = alignup(w + (NN + 1) * 4, 256);
    int* csr    = (int*)w;            w = alignup(w + (size_t)NE * 4, 256);
    float* agg  = (float*)w;          w = alignup(w + (size_t)NN * 64 * 4, 256);
    float* hcur = (float*)w;          w = alignup(w + (size_t)NN * 64 * 4, 256);
    unsigned short* hb = (unsigned short*)w; w = alignup(w + (size_t)NN * 64 * 2, 256);
    double* part = (double*)w;        w = alignup(w + 1024 * 128 * 8, 256);
    float* mu   = (float*)w;          w = alignup(w + 64 * 4, 256);
    float* inv  = (float*)w;          w = alignup(w + 64 * 4, 256);
    float* z    = (float*)w;          w = alignup(w + NG * 128 * 4, 256);
    float* wb   = (float*)w;          w = alignup(w + NWELEM * 4, 256);
    int* batch32 = (int*)w;           w = alignup(w + NN * 4, 256);

    float* x8 = agg + 3200000;                        // in agg region, past agg6 area
    unsigned long long* binbuf = (unsigned long long*)hcur;  // hcur dead until mm1

    const int* ei  = (const int*)d_in[1];
    const int* bat = (const int*)d_in[2];
    WPtrs wp;
    for (int i = 0; i < 19; i++) wp.p[i] = d_in[3 + i];

    const float* Wl1 = wb + 0,     *bl1 = wb + 384,   *Wr1 = wb + 448;
    const float* Wl2 = wb + 832,   *bl2 = wb + 4928,  *Wr2 = wb + 4992;
    const float* Wl3 = wb + 9088,  *bl3 = wb + 13184, *Wr3 = wb + 13248;
    const float* g1  = wb + 17344, *be1 = wb + 17408;
    const float* g2  = wb + 17472, *be2 = wb + 17536;
    const float* g3  = wb + 17600, *be3 = wb + 17664;
    const float* W_lin1 = wb + 17728, *b_lin1 = wb + 25920;
    const float* W_lin2 = wb + 25984, *b_lin2 = wb + 26112;

    const int NB_SCAN = (NN + 255) / 256;
    const int MMG1 = 1024;
    const int MMG  = 1024;
    const int BNB = ((NN * 16) + 255) / 256;
    const int AGG_GRID = (NN * 64 + 255) / 256;

    hipMemsetAsync(dcnt, 0, 64, stream);
    hipMemsetAsync(counts, 0, NN * 4, stream);

    k_detect_f<<<64, 256, 0, stream>>>((const unsigned short*)d_in[0], 65536, dcnt + 0, dcnt + 1);
    k_detect_f<<<16, 256, 0, stream>>>((const unsigned short*)d_in[6], 4096, dcnt + 2, dcnt + 3);
    k_detect_odd<<<16, 256, 0, stream>>>(ei, 1000, 8192, dcnt + 4);
    k_detect_odd<<<16, 256, 0, stream>>>(bat, 40000, 8192, dcnt + 5);
    k_flags<<<1, 1, 0, stream>>>(dcnt);

    k_conv_x8<<<(NN * 8 + 255) / 256, 256, 0, stream>>>(d_in[0], x8, dcnt);
    k_conv_batch<<<(NN + 255) / 256, 256, 0, stream>>>(bat, batch32, dcnt);
    k_conv_w<<<(NWELEM + 255) / 256, 256, 0, stream>>>(wp, wb, dcnt);

    // CSR: hist -> scan -> binned two-pass scatter
    k_hist<<<(NE + 255) / 256, 256, 0, stream>>>(ei, dcnt, counts);
    k_scan_block<<<NB_SCAN, 256, 0, stream>>>(counts, inblk, btot);
    k_scan_top<<<1, 512, 0, stream>>>(btot, boff, NB_SCAN);
    k_scan_final<<<NB_SCAN, 256, 0, stream>>>(inblk, boff, rowptr, cursor);
    k_bukinit<<<1, 64, 0, stream>>>(rowptr, bukcur);
    k_binA<<<1024, 256, 0, stream>>>(ei, dcnt, bukcur, binbuf);
    k_binB<<<1024, 256, 0, stream>>>(binbuf, cursor, csr);

    // layer 1 (fp32)
    k_agg6<<<AGG_GRID, 256, 0, stream>>>(x8, rowptr, csr, agg);
    k_mm1<<<MMG1, 256, 0, stream>>>(agg, x8, Wl1, bl1, Wr1, hcur, part);
    k_statred_p<<<64, 256, 0, stream>>>(part, MMG1, mu, inv);
    k_bnrelu<<<BNB, 256, 0, stream>>>((float4*)hcur, (ushort4*)hb, mu, inv, g1, be1);

    // layer 2
    k_agg64b<<<AGG_GRID, 256, 0, stream>>>(hb, rowptr, csr, agg);
    k_mm64b<<<MMG, 256, 0, stream>>>(agg, hb, Wl2, bl2, Wr2, hcur, part);
    k_statred_p<<<64, 256, 0, stream>>>(part, MMG, mu, inv);
    k_bnrelu<<<BNB, 256, 0, stream>>>((float4*)hcur, (ushort4*)hb, mu, inv, g2, be2);

    // layer 3
    k_agg64b<<<AGG_GRID, 256, 0, stream>>>(hb, rowptr, csr, agg);
    k_mm64b<<<MMG, 256, 0, stream>>>(agg, hb, Wl3, bl3, Wr3, hcur, part);
    k_statred_p<<<64, 256, 0, stream>>>(part, MMG, mu, inv);
    k_bnrelu<<<BNB, 256, 0, stream>>>((float4*)hcur, (ushort4*)hb, mu, inv, g3, be3);

    // pooling + MLP (fp32)
    k_pool<<<NG, 256, 0, stream>>>(hcur, batch32, z);
    k_mlp<<<NG, 64, 0, stream>>>(z, W_lin1, b_lin1, W_lin2, b_lin2, out);
}

// Round 15
// 1010.764 us; speedup vs baseline: 1.0861x; 1.0861x over previous
//
#include <hip/hip_runtime.h>
#include <math.h>

#define NN 100000
#define NE 3200000
#define NG 512
#define NWELEM 26114
#define DRANGE 12500   // NN / 8

__device__ __forceinline__ float b2f(unsigned short u) {
    union { float f; unsigned int i; } c; c.i = ((unsigned int)u) << 16; return c.f;
}
__device__ __forceinline__ unsigned short f2b(float f) {
    union { float f; unsigned int i; } c; c.f = f;
    unsigned int r = c.i + 0x7FFFu + ((c.i >> 16) & 1u);   // RNE
    return (unsigned short)(r >> 16);
}

// ---------------- dtype detection ----------------
__global__ void k_detect_f(const unsigned short* __restrict__ u, int n,
                           int* __restrict__ c0, int* __restrict__ c1) {
    int t = blockIdx.x * blockDim.x + threadIdx.x;
    int a = 0, b = 0;
    for (int i = t; i < n; i += gridDim.x * blockDim.x) {
        float v = b2f(u[i]);
        if (!isfinite(v) || fabsf(v) > 1.0e4f) a++;
        if (((i & 1) == 0) && u[i] == 0) b++;
    }
    if (a) atomicAdd(c0, a);
    if (b) atomicAdd(c1, b);
}
__global__ void k_detect_odd(const int* __restrict__ p, int base, int n,
                             int* __restrict__ c) {
    int t = blockIdx.x * blockDim.x + threadIdx.x;
    int a = 0;
    for (int i = t; i < n; i += gridDim.x * blockDim.x)
        if (p[base + 2 * i + 1] != 0) a++;
    if (a) atomicAdd(c, a);
}
__global__ void k_flags(int* __restrict__ cnt) {
    cnt[8]  = (cnt[0] > 50 || cnt[1] > 8000) ? 1 : 0;   // x fp32
    cnt[9]  = (cnt[2] > 50 || cnt[3] > 1000) ? 1 : 0;   // W fp32
    cnt[10] = (cnt[4] < 100) ? 1 : 0;                   // edges int64
    cnt[11] = (cnt[5] < 100) ? 1 : 0;                   // batch int64
}

// ---------------- edge accessors ----------------
__device__ __forceinline__ int e_src(const int* ei, long e, bool i64) {
    return i64 ? ei[2 * e] : ei[e];
}
__device__ __forceinline__ int e_dst(const int* ei, long e, bool i64) {
    return i64 ? ei[2 * ((long)NE + e)] : ei[(long)NE + e];
}
// nontemporal variants (scat8 only): keep the edge stream OUT of L2 so the
// csr write-window lines survive until all ~16 sibling entries arrive.
__device__ __forceinline__ int e_src_nt(const int* ei, long e, bool i64) {
    return i64 ? __builtin_nontemporal_load(&ei[2 * e])
               : __builtin_nontemporal_load(&ei[e]);
}
__device__ __forceinline__ int e_dst_nt(const int* ei, long e, bool i64) {
    return i64 ? __builtin_nontemporal_load(&ei[2 * ((long)NE + e)])
               : __builtin_nontemporal_load(&ei[(long)NE + e]);
}

// ---------------- canonicalization ----------------
__global__ void k_conv_x8(const void* __restrict__ p, float* __restrict__ dst,
                          const int* __restrict__ flags) {
    int i = blockIdx.x * blockDim.x + threadIdx.x;
    if (i >= NN * 8) return;
    int node = i >> 3, f = i & 7;
    float v = 0.f;
    if (f < 6)
        v = flags[8] ? ((const float*)p)[node * 6 + f]
                     : b2f(((const unsigned short*)p)[node * 6 + f]);
    dst[i] = v;
}
__global__ void k_conv_batch(const int* __restrict__ b, int* __restrict__ b32,
                             const int* __restrict__ flags) {
    int i = blockIdx.x * blockDim.x + threadIdx.x;
    if (i >= NN) return;
    b32[i] = flags[11] ? b[2 * i] : b[i];
}
struct WPtrs { const void* p[19]; };
__global__ void k_conv_w(WPtrs wp, float* __restrict__ dst, const int* __restrict__ flags) {
    const int L[19] = {384, 64, 384, 4096, 64, 4096, 4096, 64, 4096,
                       64, 64, 64, 64, 64, 64, 8192, 64, 128, 2};
    bool f32 = flags[9];
    int i = blockIdx.x * blockDim.x + threadIdx.x;
    if (i >= NWELEM) return;
    int ti = 0, off = i;
    while (off >= L[ti]) { off -= L[ti]; ti++; }
    const void* p = wp.p[ti];
    dst[i] = f32 ? ((const float*)p)[off] : b2f(((const unsigned short*)p)[off]);
}

// ---------------- CSR build ----------------
__global__ void k_hist(const int* __restrict__ ei, const int* __restrict__ flags,
                       int* __restrict__ counts) {
    long e = (long)blockIdx.x * blockDim.x + threadIdx.x;
    if (e >= NE) return;
    int d = e_dst(ei, e, flags[10]);
    if ((unsigned)d < NN) atomicAdd(&counts[d], 1);
}
__global__ void k_scat8(const int* __restrict__ ei, const int* __restrict__ flags,
                        int* __restrict__ cursor, int* __restrict__ csr) {
    int xcd = blockIdx.x & 7;
    int grp = blockIdx.x >> 3;
    int ngrp = gridDim.x >> 3;
    int lo = xcd * DRANGE, hi = lo + DRANGE;
    bool i64 = flags[10];
    for (long e = (long)grp * blockDim.x + threadIdx.x; e < NE;
         e += (long)ngrp * blockDim.x) {
        int d = e_dst_nt(ei, e, i64);
        if (d >= lo && d < hi) {
            int s = e_src_nt(ei, e, i64);
            int p = atomicAdd(&cursor[d], 1);
            if (p >= 0 && p < NE) csr[p] = ((unsigned)s < NN) ? s : 0;
        }
    }
}

// ---------------- scans ----------------
__global__ void k_scan_block(const int* __restrict__ counts, int* __restrict__ inblk,
                             int* __restrict__ btot) {
    __shared__ int s[256];
    int t = threadIdx.x;
    int idx = blockIdx.x * 256 + t;
    int v = (idx < NN) ? counts[idx] : 0;
    s[t] = v;
    __syncthreads();
    for (int off = 1; off < 256; off <<= 1) {
        int x = (t >= off) ? s[t - off] : 0;
        __syncthreads();
        s[t] += x;
        __syncthreads();
    }
    if (idx < NN) inblk[idx] = s[t] - v;
    if (t == 255) btot[blockIdx.x] = s[255];
}
__global__ void k_scan_top(const int* __restrict__ btot, int* __restrict__ boff, int nb) {
    __shared__ int s[512];
    int t = threadIdx.x;
    int v = (t < nb) ? btot[t] : 0;
    s[t] = v;
    __syncthreads();
    for (int off = 1; off < 512; off <<= 1) {
        int x = (t >= off) ? s[t - off] : 0;
        __syncthreads();
        s[t] += x;
        __syncthreads();
    }
    if (t < nb) boff[t] = s[t] - v;
}
__global__ void k_scan_final(const int* __restrict__ inblk, const int* __restrict__ boff,
                             int* __restrict__ rowptr, int* __restrict__ cursor) {
    int idx = blockIdx.x * 256 + threadIdx.x;
    if (idx < NN) {
        int r = inblk[idx] + boff[blockIdx.x];
        rowptr[idx] = r;
        cursor[idx] = r;
    }
    if (idx == 0) rowptr[NN] = NE;
}

// ---------------- aggregation ----------------
__global__ void k_agg6(const float* __restrict__ x8, const int* __restrict__ rowptr,
                       const int* __restrict__ csr, float* __restrict__ agg) {
    int gt = blockIdx.x * blockDim.x + threadIdx.x;
    int node = gt >> 6;
    if (node >= NN) return;
    int lane = threadIdx.x & 63;
    int f = lane & 7, es = lane >> 3;
    int r0 = rowptr[node], r1 = rowptr[node + 1];
    float acc = 0.f;
    for (int e = r0 + es; e < r1; e += 8) {
        int s = csr[e];
        acc += x8[s * 8 + f];
    }
    acc += __shfl_xor(acc, 8);
    acc += __shfl_xor(acc, 16);
    acc += __shfl_xor(acc, 32);
    int deg = r1 - r0;
    if (lane < 8) agg[node * 8 + lane] = acc / (float)(deg > 0 ? deg : 1);
}
__global__ void k_agg64b(const unsigned short* __restrict__ hb,
                         const int* __restrict__ rowptr,
                         const int* __restrict__ csr, float* __restrict__ agg) {
    int gt = blockIdx.x * blockDim.x + threadIdx.x;
    int node = gt >> 6;
    if (node >= NN) return;
    int lane = threadIdx.x & 63;
    int r0 = rowptr[node], r1 = rowptr[node + 1];
    float acc = 0.f;
    int e = r0;
    for (; e + 3 < r1; e += 4) {
        int s0 = csr[e], s1 = csr[e + 1], s2 = csr[e + 2], s3 = csr[e + 3];
        acc += b2f(hb[(long)s0 * 64 + lane]);
        acc += b2f(hb[(long)s1 * 64 + lane]);
        acc += b2f(hb[(long)s2 * 64 + lane]);
        acc += b2f(hb[(long)s3 * 64 + lane]);
    }
    for (; e < r1; e++) acc += b2f(hb[(long)csr[e] * 64 + lane]);
    int deg = r1 - r0;
    agg[(long)node * 64 + lane] = acc / (float)(deg > 0 ? deg : 1);
}

// ---------------- linear (+ fused BN stats) ----------------
__global__ void k_mm1(const float* __restrict__ agg6, const float* __restrict__ x8,
                      const float* __restrict__ Wl, const float* __restrict__ bl,
                      const float* __restrict__ Wr, float* __restrict__ pre,
                      double* __restrict__ part) {
    __shared__ float wl[6 * 64], wr[6 * 64];
    int t = threadIdx.x;
    for (int j = t; j < 384; j += 256) { wl[j] = Wl[j]; wr[j] = Wr[j]; }
    __syncthreads();
    int o = t & 63, rs = t >> 6;
    float bo = bl[o];
    double sm = 0.0, sq = 0.0;
    for (int i0 = blockIdx.x * 4; i0 < NN; i0 += gridDim.x * 4) {
        int i = i0 + rs;
        if (i < NN) {
            const float* m = &agg6[i * 8];
            const float* xr = &x8[i * 8];
            float p = bo;
#pragma unroll
            for (int k = 0; k < 6; k++) p += m[k] * wl[k * 64 + o] + xr[k] * wr[k * 64 + o];
            pre[(long)i * 64 + o] = p;
            sm += p;
            sq += (double)p * p;
        }
    }
    __shared__ double sd[256];
    sd[t] = sm; __syncthreads();
    if (t < 128) sd[t] += sd[t + 128];
    __syncthreads();
    if (t < 64) part[blockIdx.x * 128 + t] = sd[t] + sd[t + 64];
    __syncthreads();
    sd[t] = sq; __syncthreads();
    if (t < 128) sd[t] += sd[t + 128];
    __syncthreads();
    if (t < 64) part[blockIdx.x * 128 + 64 + t] = sd[t] + sd[t + 64];
}

// mm64b v4: 8 rows/wave (NN % 32 == 0), LDS weight reads amortized over 8 rows.
// No local arrays, no pointer casts (rule #20).
__global__ void k_mm64b(const float* __restrict__ agg, const unsigned short* __restrict__ hb,
                        const float* __restrict__ Wl, const float* __restrict__ bl,
                        const float* __restrict__ Wr, float* __restrict__ pre,
                        double* __restrict__ part) {
    __shared__ float wl[4096], wr[4096];
    int t = threadIdx.x;
    for (int j = t; j < 4096; j += 256) { wl[j] = Wl[j]; wr[j] = Wr[j]; }
    __syncthreads();
    int o = t & 63, wv = t >> 6;
    float bo = bl[o];
    double sm = 0.0, sq = 0.0;
    for (int i0 = blockIdx.x * 32; i0 < NN; i0 += gridDim.x * 32) {
        long i = i0 + wv * 8;                    // rows i..i+7 (100000 % 32 == 0)
        const float* m0 = agg + i * 64;          // wave-uniform bases
        const unsigned short* h0 = hb + i * 64;
        float a0 = bo, a1 = bo, a2 = bo, a3 = bo;
        float a4 = bo, a5 = bo, a6 = bo, a7 = bo;
#pragma unroll 8
        for (int k = 0; k < 64; k++) {
            float wlv = wl[k * 64 + o];
            float wrv = wr[k * 64 + o];
            a0 += m0[k]       * wlv + b2f(h0[k])       * wrv;
            a1 += m0[64 + k]  * wlv + b2f(h0[64 + k])  * wrv;
            a2 += m0[128 + k] * wlv + b2f(h0[128 + k]) * wrv;
            a3 += m0[192 + k] * wlv + b2f(h0[192 + k]) * wrv;
            a4 += m0[256 + k] * wlv + b2f(h0[256 + k]) * wrv;
            a5 += m0[320 + k] * wlv + b2f(h0[320 + k]) * wrv;
            a6 += m0[384 + k] * wlv + b2f(h0[384 + k]) * wrv;
            a7 += m0[448 + k] * wlv + b2f(h0[448 + k]) * wrv;
        }
        pre[(i + 0) * 64 + o] = a0;
        pre[(i + 1) * 64 + o] = a1;
        pre[(i + 2) * 64 + o] = a2;
        pre[(i + 3) * 64 + o] = a3;
        pre[(i + 4) * 64 + o] = a4;
        pre[(i + 5) * 64 + o] = a5;
        pre[(i + 6) * 64 + o] = a6;
        pre[(i + 7) * 64 + o] = a7;
        sm += (double)a0 + (double)a1 + (double)a2 + (double)a3
            + (double)a4 + (double)a5 + (double)a6 + (double)a7;
        sq += (double)a0 * a0 + (double)a1 * a1 + (double)a2 * a2 + (double)a3 * a3
            + (double)a4 * a4 + (double)a5 * a5 + (double)a6 * a6 + (double)a7 * a7;
    }
    __shared__ double sd[256];
    sd[t] = sm; __syncthreads();
    if (t < 128) sd[t] += sd[t + 128];
    __syncthreads();
    if (t < 64) part[blockIdx.x * 128 + t] = sd[t] + sd[t + 64];
    __syncthreads();
    sd[t] = sq; __syncthreads();
    if (t < 128) sd[t] += sd[t + 128];
    __syncthreads();
    if (t < 64) part[blockIdx.x * 128 + 64 + t] = sd[t] + sd[t + 64];
}

// parallel stat reduction: one block per channel
__global__ void k_statred_p(const double* __restrict__ part, int nb,
                            float* __restrict__ mu, float* __restrict__ inv) {
    int c = blockIdx.x;
    int t = threadIdx.x;
    double sm = 0.0, sq = 0.0;
    for (int b = t; b < nb; b += 256) {
        sm += part[(long)b * 128 + c];
        sq += part[(long)b * 128 + 64 + c];
    }
    __shared__ double s1[256], s2[256];
    s1[t] = sm; s2[t] = sq;
    __syncthreads();
    for (int off = 128; off > 0; off >>= 1) {
        if (t < off) { s1[t] += s1[t + off]; s2[t] += s2[t + off]; }
        __syncthreads();
    }
    if (t == 0) {
        double m = s1[0] / (double)NN;
        double v = s2[0] / (double)NN - m * m;
        mu[c] = (float)m;
        inv[c] = (float)rsqrt(v + 1e-5);
    }
}

// in-place BN+ReLU + bf16 pack
__global__ void k_bnrelu(float4* __restrict__ pre, ushort4* __restrict__ hb,
                         const float* __restrict__ mu, const float* __restrict__ inv,
                         const float* __restrict__ g, const float* __restrict__ be) {
    long idx = (long)blockIdx.x * blockDim.x + threadIdx.x;
    if (idx >= (long)NN * 16) return;
    int c = ((int)idx & 15) * 4;
    float4 p = pre[idx];
    p.x = fmaxf((p.x - mu[c + 0]) * inv[c + 0] * g[c + 0] + be[c + 0], 0.f);
    p.y = fmaxf((p.y - mu[c + 1]) * inv[c + 1] * g[c + 1] + be[c + 1], 0.f);
    p.z = fmaxf((p.z - mu[c + 2]) * inv[c + 2] * g[c + 2] + be[c + 2], 0.f);
    p.w = fmaxf((p.w - mu[c + 3]) * inv[c + 3] * g[c + 3] + be[c + 3], 0.f);
    pre[idx] = p;
    ushort4 u;
    u.x = f2b(p.x); u.y = f2b(p.y); u.z = f2b(p.z); u.w = f2b(p.w);
    hb[idx] = u;
}

// ---------------- pooling + MLP ----------------
__device__ __forceinline__ int lowb(const int* b, int n, int key) {
    int lo = 0, hi = n;
    while (lo < hi) {
        int m = (lo + hi) >> 1;
        if (b[m] < key) lo = m + 1; else hi = m;
    }
    return lo;
}
__global__ void k_pool(const float* __restrict__ h, const int* __restrict__ batch,
                       float* __restrict__ z) {
    int g = blockIdx.x;
    int t = threadIdx.x;
    int lo = lowb(batch, NN, g);
    int hi = lowb(batch, NN, g + 1);
    int c = t & 63, rs = t >> 6;
    float mx = 0.f, sm = 0.f;
    for (int i = lo + rs; i < hi; i += 4) {
        float v = h[(long)i * 64 + c];
        mx = fmaxf(mx, v);
        sm += v;
    }
    __shared__ float s1[256], s2[256];
    s1[t] = mx; s2[t] = sm;
    __syncthreads();
    if (t < 128) { s1[t] = fmaxf(s1[t], s1[t + 128]); s2[t] += s2[t + 128]; }
    __syncthreads();
    if (t < 64) {
        float M = fmaxf(s1[t], s1[t + 64]);
        float S = s2[t] + s2[t + 64];
        int n = hi - lo;
        z[g * 128 + t] = M;
        z[g * 128 + 64 + t] = S / (float)(n > 0 ? n : 1);
    }
}
__global__ void k_mlp(const float* __restrict__ z, const float* __restrict__ W1,
                      const float* __restrict__ b1, const float* __restrict__ W2,
                      const float* __restrict__ b2, float* __restrict__ out) {
    int g = blockIdx.x, t = threadIdx.x;
    __shared__ float zr[128], hid[64];
    zr[t] = z[g * 128 + t];
    zr[t + 64] = z[g * 128 + 64 + t];
    __syncthreads();
    float a = b1[t];
#pragma unroll 8
    for (int k = 0; k < 128; k++) a += zr[k] * W1[k * 64 + t];
    hid[t] = fmaxf(a, 0.f);
    __syncthreads();
    if (t < 2) {
        float o = b2[t];
#pragma unroll
        for (int k = 0; k < 64; k++) o += hid[k] * W2[k * 2 + t];
        out[g * 2 + t] = o;   // fp32 output (proven R10)
    }
}

// ---------------- launch ----------------
static inline char* alignup(char* p, size_t a) {
    return (char*)(((uintptr_t)p + a - 1) & ~(uintptr_t)(a - 1));
}

extern "C" void kernel_launch(void* const* d_in, const int* in_sizes, int n_in,
                              void* d_out, int out_size, void* d_ws, size_t ws_size,
                              hipStream_t stream) {
    float* out = (float*)d_out;

    char* w = (char*)d_ws;
    int* dcnt   = (int*)w;            w = alignup(w + 64, 256);
    int* counts = (int*)w;            w = alignup(w + NN * 4, 256);
    int* cursor = (int*)w;            w = alignup(w + NN * 4, 256);
    int* inblk  = (int*)w;            w = alignup(w + NN * 4, 256);
    int* btot   = (int*)w;            w = alignup(w + 512 * 4, 256);
    int* boff   = (int*)w;            w = alignup(w + 512 * 4, 256);
    int* rowptr = (int*)w;            w = alignup(w + (NN + 1) * 4, 256);
    int* csr    = (int*)w;            w = alignup(w + (size_t)NE * 4, 256);
    float* agg  = (float*)w;          w = alignup(w + (size_t)NN * 64 * 4, 256);
    float* hcur = (float*)w;          w = alignup(w + (size_t)NN * 64 * 4, 256);
    unsigned short* hb = (unsigned short*)w; w = alignup(w + (size_t)NN * 64 * 2, 256);
    double* part = (double*)w;        w = alignup(w + 1024 * 128 * 8, 256);
    float* mu   = (float*)w;          w = alignup(w + 64 * 4, 256);
    float* inv  = (float*)w;          w = alignup(w + 64 * 4, 256);
    float* z    = (float*)w;          w = alignup(w + NG * 128 * 4, 256);
    float* wb   = (float*)w;          w = alignup(w + NWELEM * 4, 256);
    int* batch32 = (int*)w;           w = alignup(w + NN * 4, 256);

    float* x8 = agg + 3200000;   // aliased into agg region beyond layer-1 agg6 area

    const int* ei  = (const int*)d_in[1];
    const int* bat = (const int*)d_in[2];
    WPtrs wp;
    for (int i = 0; i < 19; i++) wp.p[i] = d_in[3 + i];

    const float* Wl1 = wb + 0,     *bl1 = wb + 384,   *Wr1 = wb + 448;
    const float* Wl2 = wb + 832,   *bl2 = wb + 4928,  *Wr2 = wb + 4992;
    const float* Wl3 = wb + 9088,  *bl3 = wb + 13184, *Wr3 = wb + 13248;
    const float* g1  = wb + 17344, *be1 = wb + 17408;
    const float* g2  = wb + 17472, *be2 = wb + 17536;
    const float* g3  = wb + 17600, *be3 = wb + 17664;
    const float* W_lin1 = wb + 17728, *b_lin1 = wb + 25920;
    const float* W_lin2 = wb + 25984, *b_lin2 = wb + 26112;

    const int NB_SCAN = (NN + 255) / 256;
    const int MMG1 = 1024;
    const int MMG  = 1024;
    const int BNB = ((NN * 16) + 255) / 256;
    const int AGG_GRID = (NN * 64 + 255) / 256;

    hipMemsetAsync(dcnt, 0, 64, stream);
    hipMemsetAsync(counts, 0, NN * 4, stream);

    k_detect_f<<<64, 256, 0, stream>>>((const unsigned short*)d_in[0], 65536, dcnt + 0, dcnt + 1);
    k_detect_f<<<16, 256, 0, stream>>>((const unsigned short*)d_in[6], 4096, dcnt + 2, dcnt + 3);
    k_detect_odd<<<16, 256, 0, stream>>>(ei, 1000, 8192, dcnt + 4);
    k_detect_odd<<<16, 256, 0, stream>>>(bat, 40000, 8192, dcnt + 5);
    k_flags<<<1, 1, 0, stream>>>(dcnt);

    k_conv_x8<<<(NN * 8 + 255) / 256, 256, 0, stream>>>(d_in[0], x8, dcnt);
    k_conv_batch<<<(NN + 255) / 256, 256, 0, stream>>>(bat, batch32, dcnt);
    k_conv_w<<<(NWELEM + 255) / 256, 256, 0, stream>>>(wp, wb, dcnt);

    // CSR
    k_hist<<<(NE + 255) / 256, 256, 0, stream>>>(ei, dcnt, counts);
    k_scan_block<<<NB_SCAN, 256, 0, stream>>>(counts, inblk, btot);
    k_scan_top<<<1, 512, 0, stream>>>(btot, boff, NB_SCAN);
    k_scan_final<<<NB_SCAN, 256, 0, stream>>>(inblk, boff, rowptr, cursor);
    k_scat8<<<1024, 256, 0, stream>>>(ei, dcnt, cursor, csr);

    // layer 1 (fp32)
    k_agg6<<<AGG_GRID, 256, 0, stream>>>(x8, rowptr, csr, agg);
    k_mm1<<<MMG1, 256, 0, stream>>>(agg, x8, Wl1, bl1, Wr1, hcur, part);
    k_statred_p<<<64, 256, 0, stream>>>(part, MMG1, mu, inv);
    k_bnrelu<<<BNB, 256, 0, stream>>>((float4*)hcur, (ushort4*)hb, mu, inv, g1, be1);

    // layer 2
    k_agg64b<<<AGG_GRID, 256, 0, stream>>>(hb, rowptr, csr, agg);
    k_mm64b<<<MMG, 256, 0, stream>>>(agg, hb, Wl2, bl2, Wr2, hcur, part);
    k_statred_p<<<64, 256, 0, stream>>>(part, MMG, mu, inv);
    k_bnrelu<<<BNB, 256, 0, stream>>>((float4*)hcur, (ushort4*)hb, mu, inv, g2, be2);

    // layer 3
    k_agg64b<<<AGG_GRID, 256, 0, stream>>>(hb, rowptr, csr, agg);
    k_mm64b<<<MMG, 256, 0, stream>>>(agg, hb, Wl3, bl3, Wr3, hcur, part);
    k_statred_p<<<64, 256, 0, stream>>>(part, MMG, mu, inv);
    k_bnrelu<<<BNB, 256, 0, stream>>>((float4*)hcur, (ushort4*)hb, mu, inv, g3, be3);

    // pooling + MLP (fp32)
    k_pool<<<NG, 256, 0, stream>>>(hcur, batch32, z);
    k_mlp<<<NG, 64, 0, stream>>>(z, W_lin1, b_lin1, W_lin2, b_lin2, out);
}

// Round 16
// 847.791 us; speedup vs baseline: 1.2949x; 1.1922x over previous
//
#include <hip/hip_runtime.h>
#include <math.h>

#define NN 100000
#define NE 3200000
#define NG 512
#define NWELEM 26114
#define DRANGE 12500   // NN / 8

__device__ __forceinline__ float b2f(unsigned short u) {
    union { float f; unsigned int i; } c; c.i = ((unsigned int)u) << 16; return c.f;
}
__device__ __forceinline__ unsigned short f2b(float f) {
    union { float f; unsigned int i; } c; c.f = f;
    unsigned int r = c.i + 0x7FFFu + ((c.i >> 16) & 1u);   // RNE
    return (unsigned short)(r >> 16);
}

// ---------------- dtype detection ----------------
__global__ void k_detect_f(const unsigned short* __restrict__ u, int n,
                           int* __restrict__ c0, int* __restrict__ c1) {
    int t = blockIdx.x * blockDim.x + threadIdx.x;
    int a = 0, b = 0;
    for (int i = t; i < n; i += gridDim.x * blockDim.x) {
        float v = b2f(u[i]);
        if (!isfinite(v) || fabsf(v) > 1.0e4f) a++;
        if (((i & 1) == 0) && u[i] == 0) b++;
    }
    if (a) atomicAdd(c0, a);
    if (b) atomicAdd(c1, b);
}
__global__ void k_detect_odd(const int* __restrict__ p, int base, int n,
                             int* __restrict__ c) {
    int t = blockIdx.x * blockDim.x + threadIdx.x;
    int a = 0;
    for (int i = t; i < n; i += gridDim.x * blockDim.x)
        if (p[base + 2 * i + 1] != 0) a++;
    if (a) atomicAdd(c, a);
}
__global__ void k_flags(int* __restrict__ cnt) {
    cnt[8]  = (cnt[0] > 50 || cnt[1] > 8000) ? 1 : 0;   // x fp32
    cnt[9]  = (cnt[2] > 50 || cnt[3] > 1000) ? 1 : 0;   // W fp32
    cnt[10] = (cnt[4] < 100) ? 1 : 0;                   // edges int64
    cnt[11] = (cnt[5] < 100) ? 1 : 0;                   // batch int64
}

// ---------------- edge accessors ----------------
__device__ __forceinline__ int e_src(const int* ei, long e, bool i64) {
    return i64 ? ei[2 * e] : ei[e];
}
__device__ __forceinline__ int e_dst(const int* ei, long e, bool i64) {
    return i64 ? ei[2 * ((long)NE + e)] : ei[(long)NE + e];
}

// ---------------- canonicalization ----------------
__global__ void k_conv_x8(const void* __restrict__ p, float* __restrict__ dst,
                          const int* __restrict__ flags) {
    int i = blockIdx.x * blockDim.x + threadIdx.x;
    if (i >= NN * 8) return;
    int node = i >> 3, f = i & 7;
    float v = 0.f;
    if (f < 6)
        v = flags[8] ? ((const float*)p)[node * 6 + f]
                     : b2f(((const unsigned short*)p)[node * 6 + f]);
    dst[i] = v;
}
__global__ void k_conv_batch(const int* __restrict__ b, int* __restrict__ b32,
                             const int* __restrict__ flags) {
    int i = blockIdx.x * blockDim.x + threadIdx.x;
    if (i >= NN) return;
    b32[i] = flags[11] ? b[2 * i] : b[i];
}
struct WPtrs { const void* p[19]; };
__global__ void k_conv_w(WPtrs wp, float* __restrict__ dst, const int* __restrict__ flags) {
    const int L[19] = {384, 64, 384, 4096, 64, 4096, 4096, 64, 4096,
                       64, 64, 64, 64, 64, 64, 8192, 64, 128, 2};
    bool f32 = flags[9];
    int i = blockIdx.x * blockDim.x + threadIdx.x;
    if (i >= NWELEM) return;
    int ti = 0, off = i;
    while (off >= L[ti]) { off -= L[ti]; ti++; }
    const void* p = wp.p[ti];
    dst[i] = f32 ? ((const float*)p)[off] : b2f(((const unsigned short*)p)[off]);
}

// ---------------- CSR build ----------------
__global__ void k_hist(const int* __restrict__ ei, const int* __restrict__ flags,
                       int* __restrict__ counts) {
    long e = (long)blockIdx.x * blockDim.x + threadIdx.x;
    if (e >= NE) return;
    int d = e_dst(ei, e, flags[10]);
    if ((unsigned)d < NN) atomicAdd(&counts[d], 1);
}
__global__ void k_scat8(const int* __restrict__ ei, const int* __restrict__ flags,
                        int* __restrict__ cursor, int* __restrict__ csr) {
    int xcd = blockIdx.x & 7;
    int grp = blockIdx.x >> 3;
    int ngrp = gridDim.x >> 3;
    int lo = xcd * DRANGE, hi = lo + DRANGE;
    bool i64 = flags[10];
    for (long e = (long)grp * blockDim.x + threadIdx.x; e < NE;
         e += (long)ngrp * blockDim.x) {
        int d = e_dst(ei, e, i64);
        if (d >= lo && d < hi) {
            int s = e_src(ei, e, i64);
            int p = atomicAdd(&cursor[d], 1);
            if (p >= 0 && p < NE) csr[p] = ((unsigned)s < NN) ? s : 0;
        }
    }
}

// ---------------- scans ----------------
__global__ void k_scan_block(const int* __restrict__ counts, int* __restrict__ inblk,
                             int* __restrict__ btot) {
    __shared__ int s[256];
    int t = threadIdx.x;
    int idx = blockIdx.x * 256 + t;
    int v = (idx < NN) ? counts[idx] : 0;
    s[t] = v;
    __syncthreads();
    for (int off = 1; off < 256; off <<= 1) {
        int x = (t >= off) ? s[t - off] : 0;
        __syncthreads();
        s[t] += x;
        __syncthreads();
    }
    if (idx < NN) inblk[idx] = s[t] - v;
    if (t == 255) btot[blockIdx.x] = s[255];
}
__global__ void k_scan_top(const int* __restrict__ btot, int* __restrict__ boff, int nb) {
    __shared__ int s[512];
    int t = threadIdx.x;
    int v = (t < nb) ? btot[t] : 0;
    s[t] = v;
    __syncthreads();
    for (int off = 1; off < 512; off <<= 1) {
        int x = (t >= off) ? s[t - off] : 0;
        __syncthreads();
        s[t] += x;
        __syncthreads();
    }
    if (t < nb) boff[t] = s[t] - v;
}
__global__ void k_scan_final(const int* __restrict__ inblk, const int* __restrict__ boff,
                             int* __restrict__ rowptr, int* __restrict__ cursor) {
    int idx = blockIdx.x * 256 + threadIdx.x;
    if (idx < NN) {
        int r = inblk[idx] + boff[blockIdx.x];
        rowptr[idx] = r;
        cursor[idx] = r;
    }
    if (idx == 0) rowptr[NN] = NE;
}

// ---------------- aggregation ----------------
__global__ void k_agg6(const float* __restrict__ x8, const int* __restrict__ rowptr,
                       const int* __restrict__ csr, float* __restrict__ agg) {
    int gt = blockIdx.x * blockDim.x + threadIdx.x;
    int node = gt >> 6;
    if (node >= NN) return;
    int lane = threadIdx.x & 63;
    int f = lane & 7, es = lane >> 3;
    int r0 = rowptr[node], r1 = rowptr[node + 1];
    float acc = 0.f;
    for (int e = r0 + es; e < r1; e += 8) {
        int s = csr[e];
        acc += x8[s * 8 + f];
    }
    acc += __shfl_xor(acc, 8);
    acc += __shfl_xor(acc, 16);
    acc += __shfl_xor(acc, 32);
    int deg = r1 - r0;
    if (lane < 8) agg[node * 8 + lane] = acc / (float)(deg > 0 ? deg : 1);
}
__global__ void k_agg64b(const unsigned short* __restrict__ hb,
                         const int* __restrict__ rowptr,
                         const int* __restrict__ csr, float* __restrict__ agg) {
    int gt = blockIdx.x * blockDim.x + threadIdx.x;
    int node = gt >> 6;
    if (node >= NN) return;
    int lane = threadIdx.x & 63;
    int r0 = rowptr[node], r1 = rowptr[node + 1];
    float acc = 0.f;
    int e = r0;
    for (; e + 3 < r1; e += 4) {
        int s0 = csr[e], s1 = csr[e + 1], s2 = csr[e + 2], s3 = csr[e + 3];
        acc += b2f(hb[(long)s0 * 64 + lane]);
        acc += b2f(hb[(long)s1 * 64 + lane]);
        acc += b2f(hb[(long)s2 * 64 + lane]);
        acc += b2f(hb[(long)s3 * 64 + lane]);
    }
    for (; e < r1; e++) acc += b2f(hb[(long)csr[e] * 64 + lane]);
    int deg = r1 - r0;
    agg[(long)node * 64 + lane] = acc / (float)(deg > 0 ? deg : 1);
}

// ---------------- linear (+ fused BN stats) ----------------
__global__ void k_mm1(const float* __restrict__ agg6, const float* __restrict__ x8,
                      const float* __restrict__ Wl, const float* __restrict__ bl,
                      const float* __restrict__ Wr, float* __restrict__ pre,
                      double* __restrict__ part) {
    __shared__ float wl[6 * 64], wr[6 * 64];
    int t = threadIdx.x;
    for (int j = t; j < 384; j += 256) { wl[j] = Wl[j]; wr[j] = Wr[j]; }
    __syncthreads();
    int o = t & 63, rs = t >> 6;
    float bo = bl[o];
    double sm = 0.0, sq = 0.0;
    for (int i0 = blockIdx.x * 4; i0 < NN; i0 += gridDim.x * 4) {
        int i = i0 + rs;
        if (i < NN) {
            const float* m = &agg6[i * 8];
            const float* xr = &x8[i * 8];
            float p = bo;
#pragma unroll
            for (int k = 0; k < 6; k++) p += m[k] * wl[k * 64 + o] + xr[k] * wr[k * 64 + o];
            pre[(long)i * 64 + o] = p;
            sm += p;
            sq += (double)p * p;
        }
    }
    __shared__ double sd[256];
    sd[t] = sm; __syncthreads();
    if (t < 128) sd[t] += sd[t + 128];
    __syncthreads();
    if (t < 64) part[blockIdx.x * 128 + t] = sd[t] + sd[t + 64];
    __syncthreads();
    sd[t] = sq; __syncthreads();
    if (t < 128) sd[t] += sd[t + 128];
    __syncthreads();
    if (t < 64) part[blockIdx.x * 128 + 64 + t] = sd[t] + sd[t + 64];
}

// mm64b v3 (R13 winner): 4 rows/wave, LDS weights amortized, no local arrays.
__global__ void k_mm64b(const float* __restrict__ agg, const unsigned short* __restrict__ hb,
                        const float* __restrict__ Wl, const float* __restrict__ bl,
                        const float* __restrict__ Wr, float* __restrict__ pre,
                        double* __restrict__ part) {
    __shared__ float wl[4096], wr[4096];
    int t = threadIdx.x;
    for (int j = t; j < 4096; j += 256) { wl[j] = Wl[j]; wr[j] = Wr[j]; }
    __syncthreads();
    int o = t & 63, wv = t >> 6;
    float bo = bl[o];
    double sm = 0.0, sq = 0.0;
    for (int i0 = blockIdx.x * 16; i0 < NN; i0 += gridDim.x * 16) {
        long i = i0 + wv * 4;
        const float* m0 = agg + i * 64;
        const unsigned short* h0 = hb + i * 64;
        float a0 = bo, a1 = bo, a2 = bo, a3 = bo;
#pragma unroll 8
        for (int k = 0; k < 64; k++) {
            float wlv = wl[k * 64 + o];
            float wrv = wr[k * 64 + o];
            a0 += m0[k]       * wlv + b2f(h0[k])       * wrv;
            a1 += m0[64 + k]  * wlv + b2f(h0[64 + k])  * wrv;
            a2 += m0[128 + k] * wlv + b2f(h0[128 + k]) * wrv;
            a3 += m0[192 + k] * wlv + b2f(h0[192 + k]) * wrv;
        }
        pre[(i + 0) * 64 + o] = a0;
        pre[(i + 1) * 64 + o] = a1;
        pre[(i + 2) * 64 + o] = a2;
        pre[(i + 3) * 64 + o] = a3;
        sm += (double)a0 + (double)a1 + (double)a2 + (double)a3;
        sq += (double)a0 * a0 + (double)a1 * a1 + (double)a2 * a2 + (double)a3 * a3;
    }
    __shared__ double sd[256];
    sd[t] = sm; __syncthreads();
    if (t < 128) sd[t] += sd[t + 128];
    __syncthreads();
    if (t < 64) part[blockIdx.x * 128 + t] = sd[t] + sd[t + 64];
    __syncthreads();
    sd[t] = sq; __syncthreads();
    if (t < 128) sd[t] += sd[t + 128];
    __syncthreads();
    if (t < 64) part[blockIdx.x * 128 + 64 + t] = sd[t] + sd[t + 64];
}

// parallel stat reduction: one block per channel
__global__ void k_statred_p(const double* __restrict__ part, int nb,
                            float* __restrict__ mu, float* __restrict__ inv) {
    int c = blockIdx.x;
    int t = threadIdx.x;
    double sm = 0.0, sq = 0.0;
    for (int b = t; b < nb; b += 256) {
        sm += part[(long)b * 128 + c];
        sq += part[(long)b * 128 + 64 + c];
    }
    __shared__ double s1[256], s2[256];
    s1[t] = sm; s2[t] = sq;
    __syncthreads();
    for (int off = 128; off > 0; off >>= 1) {
        if (t < off) { s1[t] += s1[t + off]; s2[t] += s2[t + off]; }
        __syncthreads();
    }
    if (t == 0) {
        double m = s1[0] / (double)NN;
        double v = s2[0] / (double)NN - m * m;
        mu[c] = (float)m;
        inv[c] = (float)rsqrt(v + 1e-5);
    }
}

// in-place BN+ReLU + bf16 pack
__global__ void k_bnrelu(float4* __restrict__ pre, ushort4* __restrict__ hb,
                         const float* __restrict__ mu, const float* __restrict__ inv,
                         const float* __restrict__ g, const float* __restrict__ be) {
    long idx = (long)blockIdx.x * blockDim.x + threadIdx.x;
    if (idx >= (long)NN * 16) return;
    int c = ((int)idx & 15) * 4;
    float4 p = pre[idx];
    p.x = fmaxf((p.x - mu[c + 0]) * inv[c + 0] * g[c + 0] + be[c + 0], 0.f);
    p.y = fmaxf((p.y - mu[c + 1]) * inv[c + 1] * g[c + 1] + be[c + 1], 0.f);
    p.z = fmaxf((p.z - mu[c + 2]) * inv[c + 2] * g[c + 2] + be[c + 2], 0.f);
    p.w = fmaxf((p.w - mu[c + 3]) * inv[c + 3] * g[c + 3] + be[c + 3], 0.f);
    pre[idx] = p;
    ushort4 u;
    u.x = f2b(p.x); u.y = f2b(p.y); u.z = f2b(p.z); u.w = f2b(p.w);
    hb[idx] = u;
}

// ---------------- pooling + MLP ----------------
__device__ __forceinline__ int lowb(const int* b, int n, int key) {
    int lo = 0, hi = n;
    while (lo < hi) {
        int m = (lo + hi) >> 1;
        if (b[m] < key) lo = m + 1; else hi = m;
    }
    return lo;
}
__global__ void k_pool(const float* __restrict__ h, const int* __restrict__ batch,
                       float* __restrict__ z) {
    int g = blockIdx.x;
    int t = threadIdx.x;
    int lo = lowb(batch, NN, g);
    int hi = lowb(batch, NN, g + 1);
    int c = t & 63, rs = t >> 6;
    float mx = 0.f, sm = 0.f;
    for (int i = lo + rs; i < hi; i += 4) {
        float v = h[(long)i * 64 + c];
        mx = fmaxf(mx, v);
        sm += v;
    }
    __shared__ float s1[256], s2[256];
    s1[t] = mx; s2[t] = sm;
    __syncthreads();
    if (t < 128) { s1[t] = fmaxf(s1[t], s1[t + 128]); s2[t] += s2[t + 128]; }
    __syncthreads();
    if (t < 64) {
        float M = fmaxf(s1[t], s1[t + 64]);
        float S = s2[t] + s2[t + 64];
        int n = hi - lo;
        z[g * 128 + t] = M;
        z[g * 128 + 64 + t] = S / (float)(n > 0 ? n : 1);
    }
}
__global__ void k_mlp(const float* __restrict__ z, const float* __restrict__ W1,
                      const float* __restrict__ b1, const float* __restrict__ W2,
                      const float* __restrict__ b2, float* __restrict__ out) {
    int g = blockIdx.x, t = threadIdx.x;
    __shared__ float zr[128], hid[64];
    zr[t] = z[g * 128 + t];
    zr[t + 64] = z[g * 128 + 64 + t];
    __syncthreads();
    float a = b1[t];
#pragma unroll 8
    for (int k = 0; k < 128; k++) a += zr[k] * W1[k * 64 + t];
    hid[t] = fmaxf(a, 0.f);
    __syncthreads();
    if (t < 2) {
        float o = b2[t];
#pragma unroll
        for (int k = 0; k < 64; k++) o += hid[k] * W2[k * 2 + t];
        out[g * 2 + t] = o;   // fp32 output (proven R10)
    }
}

// ---------------- launch ----------------
static inline char* alignup(char* p, size_t a) {
    return (char*)(((uintptr_t)p + a - 1) & ~(uintptr_t)(a - 1));
}

extern "C" void kernel_launch(void* const* d_in, const int* in_sizes, int n_in,
                              void* d_out, int out_size, void* d_ws, size_t ws_size,
                              hipStream_t stream) {
    float* out = (float*)d_out;

    char* w = (char*)d_ws;
    int* dcnt   = (int*)w;            w = alignup(w + 64, 256);
    int* counts = (int*)w;            w = alignup(w + NN * 4, 256);
    int* cursor = (int*)w;            w = alignup(w + NN * 4, 256);
    int* inblk  = (int*)w;            w = alignup(w + NN * 4, 256);
    int* btot   = (int*)w;            w = alignup(w + 512 * 4, 256);
    int* boff   = (int*)w;            w = alignup(w + 512 * 4, 256);
    int* rowptr = (int*)w;            w = alignup(w + (NN + 1) * 4, 256);
    int* csr    = (int*)w;            w = alignup(w + (size_t)NE * 4, 256);
    float* agg  = (float*)w;          w = alignup(w + (size_t)NN * 64 * 4, 256);
    float* hcur = (float*)w;          w = alignup(w + (size_t)NN * 64 * 4, 256);
    unsigned short* hb = (unsigned short*)w; w = alignup(w + (size_t)NN * 64 * 2, 256);
    double* part = (double*)w;        w = alignup(w + 1024 * 128 * 8, 256);
    float* mu   = (float*)w;          w = alignup(w + 64 * 4, 256);
    float* inv  = (float*)w;          w = alignup(w + 64 * 4, 256);
    float* z    = (float*)w;          w = alignup(w + NG * 128 * 4, 256);
    float* wb   = (float*)w;          w = alignup(w + NWELEM * 4, 256);
    int* batch32 = (int*)w;           w = alignup(w + NN * 4, 256);

    float* x8 = agg + 3200000;   // aliased into agg region beyond layer-1 agg6 area

    const int* ei  = (const int*)d_in[1];
    const int* bat = (const int*)d_in[2];
    WPtrs wp;
    for (int i = 0; i < 19; i++) wp.p[i] = d_in[3 + i];

    const float* Wl1 = wb + 0,     *bl1 = wb + 384,   *Wr1 = wb + 448;
    const float* Wl2 = wb + 832,   *bl2 = wb + 4928,  *Wr2 = wb + 4992;
    const float* Wl3 = wb + 9088,  *bl3 = wb + 13184, *Wr3 = wb + 13248;
    const float* g1  = wb + 17344, *be1 = wb + 17408;
    const float* g2  = wb + 17472, *be2 = wb + 17536;
    const float* g3  = wb + 17600, *be3 = wb + 17664;
    const float* W_lin1 = wb + 17728, *b_lin1 = wb + 25920;
    const float* W_lin2 = wb + 25984, *b_lin2 = wb + 26112;

    const int NB_SCAN = (NN + 255) / 256;
    const int MMG1 = 1024;
    const int MMG  = 1024;
    const int BNB = ((NN * 16) + 255) / 256;
    const int AGG_GRID = (NN * 64 + 255) / 256;

    hipMemsetAsync(dcnt, 0, 64, stream);
    hipMemsetAsync(counts, 0, NN * 4, stream);

    k_detect_f<<<64, 256, 0, stream>>>((const unsigned short*)d_in[0], 65536, dcnt + 0, dcnt + 1);
    k_detect_f<<<16, 256, 0, stream>>>((const unsigned short*)d_in[6], 4096, dcnt + 2, dcnt + 3);
    k_detect_odd<<<16, 256, 0, stream>>>(ei, 1000, 8192, dcnt + 4);
    k_detect_odd<<<16, 256, 0, stream>>>(bat, 40000, 8192, dcnt + 5);
    k_flags<<<1, 1, 0, stream>>>(dcnt);

    k_conv_x8<<<(NN * 8 + 255) / 256, 256, 0, stream>>>(d_in[0], x8, dcnt);
    k_conv_batch<<<(NN + 255) / 256, 256, 0, stream>>>(bat, batch32, dcnt);
    k_conv_w<<<(NWELEM + 255) / 256, 256, 0, stream>>>(wp, wb, dcnt);

    // CSR
    k_hist<<<(NE + 255) / 256, 256, 0, stream>>>(ei, dcnt, counts);
    k_scan_block<<<NB_SCAN, 256, 0, stream>>>(counts, inblk, btot);
    k_scan_top<<<1, 512, 0, stream>>>(btot, boff, NB_SCAN);
    k_scan_final<<<NB_SCAN, 256, 0, stream>>>(inblk, boff, rowptr, cursor);
    k_scat8<<<1024, 256, 0, stream>>>(ei, dcnt, cursor, csr);

    // layer 1 (fp32)
    k_agg6<<<AGG_GRID, 256, 0, stream>>>(x8, rowptr, csr, agg);
    k_mm1<<<MMG1, 256, 0, stream>>>(agg, x8, Wl1, bl1, Wr1, hcur, part);
    k_statred_p<<<64, 256, 0, stream>>>(part, MMG1, mu, inv);
    k_bnrelu<<<BNB, 256, 0, stream>>>((float4*)hcur, (ushort4*)hb, mu, inv, g1, be1);

    // layer 2
    k_agg64b<<<AGG_GRID, 256, 0, stream>>>(hb, rowptr, csr, agg);
    k_mm64b<<<MMG, 256, 0, stream>>>(agg, hb, Wl2, bl2, Wr2, hcur, part);
    k_statred_p<<<64, 256, 0, stream>>>(part, MMG, mu, inv);
    k_bnrelu<<<BNB, 256, 0, stream>>>((float4*)hcur, (ushort4*)hb, mu, inv, g2, be2);

    // layer 3
    k_agg64b<<<AGG_GRID, 256, 0, stream>>>(hb, rowptr, csr, agg);
    k_mm64b<<<MMG, 256, 0, stream>>>(agg, hb, Wl3, bl3, Wr3, hcur, part);
    k_statred_p<<<64, 256, 0, stream>>>(part, MMG, mu, inv);
    k_bnrelu<<<BNB, 256, 0, stream>>>((float4*)hcur, (ushort4*)hb, mu, inv, g3, be3);

    // pooling + MLP (fp32)
    k_pool<<<NG, 256, 0, stream>>>(hcur, batch32, z);
    k_mlp<<<NG, 64, 0, stream>>>(z, W_lin1, b_lin1, W_lin2, b_lin2, out);
}